// Round 3
// baseline (4437.955 us; speedup 1.0000x reference)
//
#include <hip/hip_runtime.h>
#include <hip/hip_fp16.h>
#include <cstdint>
#include <cstddef>

// ---------------------------------------------------------------------------
// CNN (conv1+pool, conv2+pool) -> seq [256][256][32]
// NTM scan: 128 blocks x 1024 threads, 2 batch/block, 1 block/CU (LDS 158KB).
// LSTM weights fp16 k-pair packed, split per thread (40 pairs x 4 cols):
//   pairs  0..15 -> 64 VGPRs (persistent, static-indexed)
//   pairs 16..21 -> LDS (96KB, loaded once)
//   pairs 22..39 -> streamed from L2 each step (295KB/CU/step, coalesced 16B)
// z-GEMM via v_dot2_f32_f16 (f32 accumulate).
// ---------------------------------------------------------------------------

#define MW    20
#define NLOC  128
#define ZC    1024
#define PC    92
#define CLIPV 20.0f

__device__ __forceinline__ float sigmoidf_(float x) { return 1.0f / (1.0f + expf(-x)); }
__device__ __forceinline__ float softplusf_(float x) { return log1pf(expf(x)); }

__device__ __forceinline__ float dot2f(uint32_t w, uint32_t a, float c) {
    asm("v_dot2_f32_f16 %0, %1, %2, %0" : "+v"(c) : "v"(w), "v"(a));
    return c;
}

// ---------------------------------------------------------------------------
// Weight packing. K layout (pairs pr = k/2, K padded 308->320, 160 pairs):
//   k 0..31 xt (pr 0..15), k 32..51 reads (pr 16..25), k 52..307 h (pr 26..153),
//   k 308..319 zero pad (pr 154..159).
// Thread t = kq*256 + c (kq=t>>8) owns pairs kq*40+p (p 0..39), cols c+256*m.
// ---------------------------------------------------------------------------
__device__ __forceinline__ float wval(const float* wx, const float* wh, int k, int col) {
    if (k < 52)  return wx[k * ZC + col];
    if (k < 308) return wh[(k - 52) * ZC + col];
    return 0.0f;
}
__device__ __forceinline__ uint32_t packpr(const float* wx, const float* wh, int pr, int col) {
    __half2 h = __floats2half2_rn(wval(wx, wh, 2 * pr, col), wval(wx, wh, 2 * pr + 1, col));
    return *reinterpret_cast<uint32_t*>(&h);
}

__global__ __launch_bounds__(256) void prep_pack(const float* __restrict__ wx,
                                                 const float* __restrict__ wh,
                                                 const float* __restrict__ hw,
                                                 uint32_t* __restrict__ WregG,  // [64][1024]
                                                 uint32_t* __restrict__ WlG,    // [6][1024][4]
                                                 uint32_t* __restrict__ WstG,   // [18][1024][4]
                                                 uint32_t* __restrict__ hw2G) { // [128][92]
    int idx = blockIdx.x * 256 + threadIdx.x;
    if (idx < 65536) {                      // Wreg: j = p*4+m
        int j = idx >> 10, tt = idx & 1023;
        int kq = tt >> 8, c = tt & 255, p = j >> 2, m = j & 3;
        WregG[idx] = packpr(wx, wh, kq * 40 + p, c + 256 * m);
    } else if (idx < 90112) {               // Wl: pairs 16..21
        int q = idx - 65536;
        int m = q & 3, tt = (q >> 2) & 1023, pl = q >> 12;
        int kq = tt >> 8, c = tt & 255;
        WlG[q] = packpr(wx, wh, kq * 40 + 16 + pl, c + 256 * m);
    } else if (idx < 163840) {              // Wst: pairs 22..39
        int q = idx - 90112;
        int m = q & 3, tt = (q >> 2) & 1023, ps = q >> 12;
        int kq = tt >> 8, c = tt & 255;
        WstG[q] = packpr(wx, wh, kq * 40 + 22 + ps, c + 256 * m);
    } else if (idx < 163840 + 11776) {      // hw2: u-pairs of head_w
        int q = idx - 163840;
        int up = q / 92, col = q - up * 92;
        __half2 h = __floats2half2_rn(hw[(2 * up) * PC + col], hw[(2 * up + 1) * PC + col]);
        hw2G[q] = *reinterpret_cast<uint32_t*>(&h);
    }
}

// conv1 3x3 (1->16) SAME + relu + maxpool2
__global__ __launch_bounds__(256) void conv1_pool(const float* __restrict__ in,
                                                  const float* __restrict__ w,
                                                  const float* __restrict__ bias,
                                                  float* __restrict__ out) {
    int idx = blockIdx.x * 256 + threadIdx.x;
    if (idx >= 256 * 32 * 32 * 16) return;
    int c = idx & 15, x = (idx >> 4) & 31, y = (idx >> 9) & 31, b = idx >> 14;
    const float* inb = in + (size_t)b * 4096;
    float bv = bias[c];
    float mx = 0.0f;
    #pragma unroll
    for (int dy = 0; dy < 2; ++dy)
    #pragma unroll
    for (int dx = 0; dx < 2; ++dx) {
        int oy = 2 * y + dy, ox = 2 * x + dx;
        float s = bv;
        #pragma unroll
        for (int ky = 0; ky < 3; ++ky) {
            int iy = oy + ky - 1;
            if (iy < 0 || iy > 63) continue;
            #pragma unroll
            for (int kx = 0; kx < 3; ++kx) {
                int ix = ox + kx - 1;
                if (ix < 0 || ix > 63) continue;
                s = fmaf(inb[iy * 64 + ix], w[(ky * 3 + kx) * 16 + c], s);
            }
        }
        mx = fmaxf(mx, fmaxf(s, 0.0f));
    }
    out[idx] = mx;
}

// conv2 3x3 (16->32) SAME + relu + maxpool2
__global__ __launch_bounds__(256) void conv2_pool(const float* __restrict__ p1,
                                                  const float* __restrict__ w,
                                                  const float* __restrict__ bias,
                                                  float* __restrict__ seq) {
    int idx = blockIdx.x * 256 + threadIdx.x;
    if (idx >= 256 * 16 * 16 * 32) return;
    int c = idx & 31, x = (idx >> 5) & 15, y = (idx >> 9) & 15, b = idx >> 13;
    const float* pb = p1 + (size_t)b * (32 * 32 * 16);
    float bv = bias[c];
    float mx = 0.0f;
    #pragma unroll
    for (int dy = 0; dy < 2; ++dy)
    #pragma unroll
    for (int dx = 0; dx < 2; ++dx) {
        int oy = 2 * y + dy, ox = 2 * x + dx;
        float s = bv;
        for (int ky = 0; ky < 3; ++ky) {
            int iy = oy + ky - 1;
            if (iy < 0 || iy > 31) continue;
            for (int kx = 0; kx < 3; ++kx) {
                int ix = ox + kx - 1;
                if (ix < 0 || ix > 31) continue;
                const float* pin = pb + (iy * 32 + ix) * 16;
                const float* pw  = w + (ky * 3 + kx) * 16 * 32 + c;
                #pragma unroll
                for (int ci2 = 0; ci2 < 16; ++ci2)
                    s = fmaf(pin[ci2], pw[ci2 * 32], s);
            }
        }
        mx = fmaxf(mx, fmaxf(s, 0.0f));
    }
    seq[idx] = mx;
}

// ---------------------------------------------------------------------------
// Persistent NTM scan.
// ---------------------------------------------------------------------------
#define PSCLIP(b_, col_) fminf(fmaxf(pp[0][b_][col_] + pp[1][b_][col_] + pp[2][b_][col_] + pp[3][b_][col_] + hb[col_], -CLIPV), CLIPV)

__global__ __launch_bounds__(1024, 4) void ntm_scan3(
    const float* __restrict__ seq,
    const uint32_t* __restrict__ WregG,
    const uint32_t* __restrict__ WlG,
    const uint32_t* __restrict__ WstG,
    const uint32_t* __restrict__ hw2G,
    const float* __restrict__ lb,
    const float* __restrict__ hb,
    const float* __restrict__ ow,
    const float* __restrict__ ob,
    const float* __restrict__ dw,
    const float* __restrict__ db,
    float* __restrict__ out)          // [256][2]
{
    __shared__ uint32_t Wl[6 * 1024 * 4];       // 98304 B
    __shared__ float zpart[4][2][ZC];           // 32768 B
    __shared__ _Float16 ci2h[2][320];           // 1280 B
    __shared__ float Msh[2][MW][132];           // 21120 B
    __shared__ float hsh[2][256];               // 2048 B
    __shared__ float rds[2][MW];                // 160 B
    __shared__ float wprev[2][2][NLOC];         // 2048 B
    __shared__ float pp[4][2][PC];              // 2944 B
    __shared__ float kvs[2][2][MW];             // 320 B
    __shared__ float evs[2][MW], avs[2][MW];    // 320 B
    __shared__ float o8[2][8];                  // 64 B

    const int t = threadIdx.x;
    const int bs0 = blockIdx.x * 2;
    const int kq = t >> 8, c = t & 255;

    // ---- one-time loads ----
    for (int i = t; i < 24576; i += 1024) Wl[i] = WlG[i];
    uint32_t wr[64];
    #pragma unroll
    for (int j = 0; j < 64; ++j) wr[j] = WregG[j * 1024 + t];

    for (int i = t; i < 2 * 320; i += 1024) {
        int b = i / 320, k = i - b * 320;
        _Float16 v;
        if (k < 32)      v = (_Float16)seq[(size_t)(bs0 + b) * 8192 + k];
        else if (k < 52) v = (_Float16)1e-6f;
        else             v = (_Float16)0.0f;
        ci2h[b][k] = v;
    }
    for (int i = t; i < 2 * MW * 132; i += 1024) {
        int b = i / (MW * 132), r = i - b * (MW * 132);
        Msh[b][r / 132][r - (r / 132) * 132] = 1e-6f;
    }
    if (t < 512) {
        int b = t >> 8, r = t & 255;
        wprev[b][r >> 7][r & 127] = 1.0f / 128.0f;
    }
    float c_reg = 0.0f;
    __syncthreads();

    const uint4* WlV  = (const uint4*)Wl;
    const uint4* WstV = (const uint4*)WstG;
    const uint32_t* ci2u0 = (const uint32_t*)&ci2h[0][0];
    const uint32_t* ci2u1 = (const uint32_t*)&ci2h[1][0];

    for (int step = 0; step < 256; ++step) {
        // ---- P1: z = ci @ [Wx;Wh] via dot2, 4-way K split ----
        {
            float acc[4][2];
            #pragma unroll
            for (int m = 0; m < 4; ++m) { acc[m][0] = 0.0f; acc[m][1] = 0.0f; }
            const uint4* cap = (const uint4*)(ci2u0 + 40 * kq);
            const uint4* cbp = (const uint4*)(ci2u1 + 40 * kq);
            #pragma unroll
            for (int cc = 0; cc < 10; ++cc) {
                uint4 a4 = cap[cc];
                uint4 b4 = cbp[cc];
                uint32_t aa[4] = {a4.x, a4.y, a4.z, a4.w};
                uint32_t bb[4] = {b4.x, b4.y, b4.z, b4.w};
                #pragma unroll
                for (int q = 0; q < 4; ++q) {
                    const int p = 4 * cc + q;
                    uint32_t w0, w1, w2, w3;
                    if (p < 16) {
                        w0 = wr[p * 4]; w1 = wr[p * 4 + 1]; w2 = wr[p * 4 + 2]; w3 = wr[p * 4 + 3];
                    } else if (p < 22) {
                        uint4 w4 = WlV[(p - 16) * 1024 + t];
                        w0 = w4.x; w1 = w4.y; w2 = w4.z; w3 = w4.w;
                    } else {
                        uint4 w4 = WstV[(p - 22) * 1024 + t];
                        w0 = w4.x; w1 = w4.y; w2 = w4.z; w3 = w4.w;
                    }
                    acc[0][0] = dot2f(w0, aa[q], acc[0][0]);
                    acc[1][0] = dot2f(w1, aa[q], acc[1][0]);
                    acc[2][0] = dot2f(w2, aa[q], acc[2][0]);
                    acc[3][0] = dot2f(w3, aa[q], acc[3][0]);
                    acc[0][1] = dot2f(w0, bb[q], acc[0][1]);
                    acc[1][1] = dot2f(w1, bb[q], acc[1][1]);
                    acc[2][1] = dot2f(w2, bb[q], acc[2][1]);
                    acc[3][1] = dot2f(w3, bb[q], acc[3][1]);
                }
            }
            #pragma unroll
            for (int m = 0; m < 4; ++m) {
                zpart[kq][0][c + 256 * m] = acc[m][0];
                zpart[kq][1][c + 256 * m] = acc[m][1];
            }
        }
        __syncthreads();   // B1

        // ---- P2: LSTM update (+ next-xt prefetch on spare threads) ----
        if (t < 512) {
            int b = t >> 8, u = t & 255;
            float zi = lb[u], zf = lb[256 + u], zg = lb[512 + u], zo = lb[768 + u];
            #pragma unroll
            for (int q = 0; q < 4; ++q) {
                zi += zpart[q][b][u];       zf += zpart[q][b][256 + u];
                zg += zpart[q][b][512 + u]; zo += zpart[q][b][768 + u];
            }
            float cg = sigmoidf_(zf) * c_reg + sigmoidf_(zi) * tanhf(zg);
            c_reg = cg;
            float h = sigmoidf_(zo) * tanhf(cg);
            hsh[b][u] = h;
            ci2h[b][52 + u] = (_Float16)h;
        } else if (t < 576 && step < 255) {
            int q = t - 512, b = q >> 5, cc = q & 31;
            ci2h[b][cc] = (_Float16)seq[(size_t)(bs0 + b) * 8192 + (size_t)(step + 1) * 32 + cc];
        }
        __syncthreads();   // B2

        // ---- P3: head-param GEMM partials via dot2 (4-way u split) ----
        if (t < 736) {
            int kq2 = t / 184, r = t - kq2 * 184, b = r / 92, col = r - b * 92;
            const uint32_t* hwp = hw2G + kq2 * 32 * 92 + col;
            const uint32_t* hbp = (b ? ci2u1 : ci2u0) + 26 + kq2 * 32;
            float s = 0.0f;
            #pragma unroll 8
            for (int uu = 0; uu < 32; ++uu)
                s = dot2f(hwp[uu * 92], hbp[uu], s);
            pp[kq2][b][col] = s;
        }
        __syncthreads();   // B3

        // ---- P4a: kv / erase / add vectors ----
        if (t < 80) {
            int b = t / 40, hh = (t / 20) & 1, wi = t % 20;
            kvs[b][hh][wi] = tanhf(PSCLIP(b, hh * 26 + wi));
        } else if (t >= 128 && t < 208) {
            int q = t - 128, b = q / 40, r2 = q % 40;
            if (r2 < 20) evs[b][r2]      = sigmoidf_(PSCLIP(b, 52 + r2));
            else         avs[b][r2 - 20] = tanhf(PSCLIP(b, 72 + (r2 - 20)));
        }
        __syncthreads();   // B4

        // ---- P4b: addressing, one wave per (b,hh); lane holds n=2l,2l+1 ----
        if (t < 256) {
            const int l = t & 63;
            const int b = t >> 7, hh = (t >> 6) & 1;
            const int hc = hh * 26;
            float beta  = softplusf_(PSCLIP(b, hc + 20));
            float g     = sigmoidf_(PSCLIP(b, hc + 21));
            float s0r = PSCLIP(b, hc + 22), s1r = PSCLIP(b, hc + 23), s2r = PSCLIP(b, hc + 24);
            float mS = fmaxf(s0r, fmaxf(s1r, s2r));
            float q0 = expf(s0r - mS), q1 = expf(s1r - mS), q2 = expf(s2r - mS);
            float qin = 1.0f / (q0 + q1 + q2);
            float sh0 = q0 * qin, sh1 = q1 * qin, sh2 = q2 * qin;
            float gamma = softplusf_(PSCLIP(b, hc + 25)) + 1.0f;

            float kvr[20]; float kn2 = 0.0f;
            #pragma unroll
            for (int wi = 0; wi < 20; ++wi) { kvr[wi] = kvs[b][hh][wi]; kn2 = fmaf(kvr[wi], kvr[wi], kn2); }
            float kden = sqrtf(kn2) + 1e-8f;

            float d0 = 0, d1 = 0, m20 = 0, m21 = 0;
            #pragma unroll
            for (int wi = 0; wi < 20; ++wi) {
                float2 mv = *reinterpret_cast<const float2*>(&Msh[b][wi][2 * l]);
                d0  = fmaf(kvr[wi], mv.x, d0);  d1  = fmaf(kvr[wi], mv.y, d1);
                m20 = fmaf(mv.x, mv.x, m20);    m21 = fmaf(mv.y, mv.y, m21);
            }
            float x0 = beta * (d0 / ((sqrtf(m20) + 1e-8f) * kden));
            float x1 = beta * (d1 / ((sqrtf(m21) + 1e-8f) * kden));
            float mx = fmaxf(x0, x1);
            #pragma unroll
            for (int o = 1; o < 64; o <<= 1) mx = fmaxf(mx, __shfl_xor(mx, o, 64));
            float e0 = expf(x0 - mx), e1 = expf(x1 - mx);
            float se = e0 + e1;
            #pragma unroll
            for (int o = 1; o < 64; o <<= 1) se += __shfl_xor(se, o, 64);
            float inv = 1.0f / se;
            float2 wpv = *reinterpret_cast<const float2*>(&wprev[b][hh][2 * l]);
            float wg0 = g * (e0 * inv) + (1.0f - g) * wpv.x;
            float wg1 = g * (e1 * inv) + (1.0f - g) * wpv.y;
            float wgm = __shfl(wg1, (l + 63) & 63, 64);
            float wgp = __shfl(wg0, (l + 1) & 63, 64);
            float wt0 = sh0 * wg1 + sh1 * wg0 + sh2 * wgm;
            float wt1 = sh0 * wgp + sh1 * wg1 + sh2 * wg0;
            float wpw0 = expf(gamma * logf(wt0 + 1e-8f));
            float wpw1 = expf(gamma * logf(wt1 + 1e-8f));
            float ssum = wpw0 + wpw1;
            #pragma unroll
            for (int o = 1; o < 64; o <<= 1) ssum += __shfl_xor(ssum, o, 64);
            float rin = 1.0f / ssum;
            *reinterpret_cast<float2*>(&wprev[b][hh][2 * l]) = make_float2(wpw0 * rin, wpw1 * rin);
        }
        __syncthreads();   // B5

        // ---- P5: reads = w_read @ M, 16-lane groups, wave-local reduce ----
        if (t < 640) {
            int g = t >> 4, l16 = t & 15;
            int b = g / 20, wi = g - b * 20;
            int n0 = l16 * 8;
            float s = 0.0f;
            #pragma unroll
            for (int n = n0; n < n0 + 8; ++n)
                s = fmaf(wprev[b][0][n], Msh[b][wi][n], s);
            #pragma unroll
            for (int o = 1; o < 16; o <<= 1) s += __shfl_xor(s, o, 64);
            if (l16 == 0) { rds[b][wi] = s; ci2h[b][32 + wi] = (_Float16)s; }
        }
        __syncthreads();   // B6

        // ---- P6: memory erase+add ----
        for (int i = t; i < 2 * MW * NLOC; i += 1024) {
            int b = i / 2560, r = i - b * 2560, wi = r >> 7, n = r & 127;
            float wwn = wprev[b][1][n];
            Msh[b][wi][n] = Msh[b][wi][n] * (1.0f - wwn * evs[b][wi]) + wwn * avs[b][wi];
        }
        __syncthreads();   // B7
    }

    // ---- final NTM output head + dense + softmax ----
    if (t < 16) {
        int b = t >> 3, o = t & 7;
        float s = ob[o];
        for (int u = 0; u < 256; ++u) s = fmaf(hsh[b][u], ow[u * 8 + o], s);
        #pragma unroll
        for (int wi = 0; wi < 20; ++wi) s = fmaf(rds[b][wi], ow[(256 + wi) * 8 + o], s);
        o8[b][o] = fminf(fmaxf(s, -CLIPV), CLIPV);
    }
    __syncthreads();
    if (t < 2) {
        float l0 = db[0], l1 = db[1];
        #pragma unroll
        for (int k = 0; k < 8; ++k) {
            float v = o8[t][k];
            l0 = fmaf(v, dw[k * 2 + 0], l0);
            l1 = fmaf(v, dw[k * 2 + 1], l1);
        }
        float m = fmaxf(l0, l1);
        float q0 = expf(l0 - m), q1 = expf(l1 - m);
        float inv = 1.0f / (q0 + q1);
        out[(bs0 + t) * 2 + 0] = q0 * inv;
        out[(bs0 + t) * 2 + 1] = q1 * inv;
    }
}

extern "C" void kernel_launch(void* const* d_in, const int* in_sizes, int n_in,
                              void* d_out, int out_size, void* d_ws, size_t ws_size,
                              hipStream_t stream) {
    const float* inputs = (const float*)d_in[0];
    const float* c1w = (const float*)d_in[1];
    const float* c1b = (const float*)d_in[2];
    const float* c2w = (const float*)d_in[3];
    const float* c2b = (const float*)d_in[4];
    const float* lwx = (const float*)d_in[5];
    const float* lwh = (const float*)d_in[6];
    const float* lb  = (const float*)d_in[7];
    const float* hw  = (const float*)d_in[8];
    const float* hb  = (const float*)d_in[9];
    const float* ow  = (const float*)d_in[10];
    const float* ob  = (const float*)d_in[11];
    const float* dw  = (const float*)d_in[12];
    const float* db  = (const float*)d_in[13];
    float* out = (float*)d_out;

    float* ws    = (float*)d_ws;
    float* p1    = ws;                         // 4,194,304 f
    float* seq   = ws + 4194304;               // 2,097,152 f
    uint32_t* WregG = (uint32_t*)(ws + 6291456);   //  65,536 u32
    uint32_t* WlG   = WregG + 65536;               //  24,576 u32
    uint32_t* WstG  = WlG + 24576;                 //  73,728 u32
    uint32_t* hw2G  = WstG + 73728;                //  11,776 u32

    hipLaunchKernelGGL(prep_pack,  dim3(686),   dim3(256),  0, stream,
                       lwx, lwh, hw, WregG, WlG, WstG, hw2G);
    hipLaunchKernelGGL(conv1_pool, dim3(16384), dim3(256),  0, stream, inputs, c1w, c1b, p1);
    hipLaunchKernelGGL(conv2_pool, dim3(8192),  dim3(256),  0, stream, p1, c2w, c2b, seq);
    hipLaunchKernelGGL(ntm_scan3,  dim3(128),   dim3(1024), 0, stream,
                       seq, WregG, WlG, WstG, hw2G, lb, hb, ow, ob, dw, db, out);
}

// Round 4
// 3651.451 us; speedup vs baseline: 1.2154x; 1.2154x over previous
//
#include <hip/hip_runtime.h>
#include <hip/hip_fp16.h>
#include <cstdint>
#include <cstddef>

// ---------------------------------------------------------------------------
// CNN (conv1+pool, conv2+pool) -> seq [256][256][32]
// NTM scan: 256 blocks x 512 threads, 1 batch/block, 1 block/CU.
// __launch_bounds__(512,2) -> 2 waves/SIMD -> 256 VGPR/wave budget.
// LSTM weights fp16 k-pair packed. Per thread (40 pairs x 8 cols):
//   pairs  0..15 -> 128 u32 in VGPRs (persistent, 256 KB/CU)
//   pairs 16..22 -> LDS (112 KB, loaded once)
//   pairs 23..39 -> streamed from L2 each step (272 KB/CU/step, 16B coalesced)
// z-GEMM via v_dot2_f32_f16 (f32 accumulate).
// ---------------------------------------------------------------------------

#define MW    20
#define NLOC  128
#define ZC    1024
#define PC    92
#define CLIPV 20.0f

__device__ __forceinline__ float sigmoidf_(float x) { return 1.0f / (1.0f + expf(-x)); }
__device__ __forceinline__ float softplusf_(float x) { return log1pf(expf(x)); }

__device__ __forceinline__ float dot2f(uint32_t w, uint32_t a, float c) {
    asm("v_dot2_f32_f16 %0, %1, %2, %0" : "+v"(c) : "v"(w), "v"(a));
    return c;
}

// ---------------------------------------------------------------------------
// Weight packing. K pairs pr = k/2 (K 308 -> 320 pad, 160 pairs):
//   k 0..31 xt, 32..51 reads, 52..307 h, 308..319 zero pad.
// Thread t (0..511): kq = t>>7, c = t&127. Owns pairs kq*40+p (p 0..39),
// cols c + 128*(m4*4+x), m4 0..1, x 0..3.
// WallG layout: uint4 index (p*2+m4)*512 + t.
// ---------------------------------------------------------------------------
__device__ __forceinline__ float wval(const float* wx, const float* wh, int k, int col) {
    if (k < 52)  return wx[k * ZC + col];
    if (k < 308) return wh[(k - 52) * ZC + col];
    return 0.0f;
}
__device__ __forceinline__ uint32_t packpr(const float* wx, const float* wh, int pr, int col) {
    __half2 h = __floats2half2_rn(wval(wx, wh, 2 * pr, col), wval(wx, wh, 2 * pr + 1, col));
    return *reinterpret_cast<uint32_t*>(&h);
}

__global__ __launch_bounds__(256) void prep_pack(const float* __restrict__ wx,
                                                 const float* __restrict__ wh,
                                                 const float* __restrict__ hw,
                                                 uint32_t* __restrict__ WallG,  // [40][2][512][4]
                                                 uint32_t* __restrict__ hw2G) { // [128][92]
    int idx = blockIdx.x * 256 + threadIdx.x;
    if (idx < 163840) {
        int x = idx & 3, t = (idx >> 2) & 511, m4 = (idx >> 11) & 1, p = idx >> 12;
        int pr  = (t >> 7) * 40 + p;
        int col = (t & 127) + 128 * (m4 * 4 + x);
        WallG[idx] = packpr(wx, wh, pr, col);
    } else if (idx < 163840 + 11776) {
        int q = idx - 163840;
        int up = q / 92, col = q - up * 92;
        __half2 h = __floats2half2_rn(hw[(2 * up) * PC + col], hw[(2 * up + 1) * PC + col]);
        hw2G[q] = *reinterpret_cast<uint32_t*>(&h);
    }
}

// conv1 3x3 (1->16) SAME + relu + maxpool2
__global__ __launch_bounds__(256) void conv1_pool(const float* __restrict__ in,
                                                  const float* __restrict__ w,
                                                  const float* __restrict__ bias,
                                                  float* __restrict__ out) {
    int idx = blockIdx.x * 256 + threadIdx.x;
    if (idx >= 256 * 32 * 32 * 16) return;
    int c = idx & 15, x = (idx >> 4) & 31, y = (idx >> 9) & 31, b = idx >> 14;
    const float* inb = in + (size_t)b * 4096;
    float bv = bias[c];
    float mx = 0.0f;
    #pragma unroll
    for (int dy = 0; dy < 2; ++dy)
    #pragma unroll
    for (int dx = 0; dx < 2; ++dx) {
        int oy = 2 * y + dy, ox = 2 * x + dx;
        float s = bv;
        #pragma unroll
        for (int ky = 0; ky < 3; ++ky) {
            int iy = oy + ky - 1;
            if (iy < 0 || iy > 63) continue;
            #pragma unroll
            for (int kx = 0; kx < 3; ++kx) {
                int ix = ox + kx - 1;
                if (ix < 0 || ix > 63) continue;
                s = fmaf(inb[iy * 64 + ix], w[(ky * 3 + kx) * 16 + c], s);
            }
        }
        mx = fmaxf(mx, fmaxf(s, 0.0f));
    }
    out[idx] = mx;
}

// conv2 3x3 (16->32) SAME + relu + maxpool2
__global__ __launch_bounds__(256) void conv2_pool(const float* __restrict__ p1,
                                                  const float* __restrict__ w,
                                                  const float* __restrict__ bias,
                                                  float* __restrict__ seq) {
    int idx = blockIdx.x * 256 + threadIdx.x;
    if (idx >= 256 * 16 * 16 * 32) return;
    int c = idx & 31, x = (idx >> 5) & 15, y = (idx >> 9) & 15, b = idx >> 13;
    const float* pb = p1 + (size_t)b * (32 * 32 * 16);
    float bv = bias[c];
    float mx = 0.0f;
    #pragma unroll
    for (int dy = 0; dy < 2; ++dy)
    #pragma unroll
    for (int dx = 0; dx < 2; ++dx) {
        int oy = 2 * y + dy, ox = 2 * x + dx;
        float s = bv;
        for (int ky = 0; ky < 3; ++ky) {
            int iy = oy + ky - 1;
            if (iy < 0 || iy > 31) continue;
            for (int kx = 0; kx < 3; ++kx) {
                int ix = ox + kx - 1;
                if (ix < 0 || ix > 31) continue;
                const float* pin = pb + (iy * 32 + ix) * 16;
                const float* pw  = w + (ky * 3 + kx) * 16 * 32 + c;
                #pragma unroll
                for (int ci2 = 0; ci2 < 16; ++ci2)
                    s = fmaf(pin[ci2], pw[ci2 * 32], s);
            }
        }
        mx = fmaxf(mx, fmaxf(s, 0.0f));
    }
    seq[idx] = mx;
}

// ---------------------------------------------------------------------------
// Persistent NTM scan: 1 batch/block, 512 threads.
// ---------------------------------------------------------------------------
#define PSCLIP1(col_) fminf(fmaxf(pp[0][col_] + pp[1][col_] + pp[2][col_] + pp[3][col_] + hb[col_], -CLIPV), CLIPV)

__global__ __launch_bounds__(512, 2) void ntm_scan4(
    const float* __restrict__ seq,
    const uint32_t* __restrict__ WallG,
    const uint32_t* __restrict__ hw2G,
    const float* __restrict__ lb,
    const float* __restrict__ hb,
    const float* __restrict__ ow,
    const float* __restrict__ ob,
    const float* __restrict__ dw,
    const float* __restrict__ db,
    float* __restrict__ out)          // [256][2]
{
    __shared__ uint4 Wl4[7 * 2 * 512];             // 114688 B  (pairs 16..22)
    __shared__ float zpart[4][ZC];                 // 16384 B
    __shared__ __align__(16) _Float16 ci2h[320];   // 640 B
    __shared__ float Msh[MW][132];                 // 10560 B
    __shared__ float hsh[256];                     // 1024 B
    __shared__ float rds[MW];                      // 80 B
    __shared__ float wprev[2][NLOC];               // 1024 B
    __shared__ float pp[4][PC];                    // 1472 B
    __shared__ float kvs[2][MW];                   // 160 B
    __shared__ float evs[MW], avs[MW];             // 160 B
    __shared__ float o8[8];                        // 32 B

    const int t  = threadIdx.x;
    const int bb = blockIdx.x;
    const int kq = t >> 7, c = t & 127;

    const uint4* WallV = (const uint4*)WallG;

    // ---- persistent register weights: pairs 0..15 (128 u32 = 32 uint4) ----
    uint4 wr4[32];
    #pragma unroll
    for (int j = 0; j < 32; ++j) wr4[j] = WallV[j * 512 + t];

    // ---- one-time LDS weight load: pairs 16..22 ----
    for (int i = t; i < 7168; i += 512) Wl4[i] = WallV[16384 + i];

    // ---- init state ----
    for (int i = t; i < 320; i += 512) {
        _Float16 v;
        if (i < 32)      v = (_Float16)seq[(size_t)bb * 8192 + i];
        else if (i < 52) v = (_Float16)1e-6f;
        else             v = (_Float16)0.0f;
        ci2h[i] = v;
    }
    for (int i = t; i < MW * 132; i += 512)
        Msh[i / 132][i - (i / 132) * 132] = 1e-6f;
    if (t < 256) wprev[t >> 7][t & 127] = 1.0f / 128.0f;
    float c_reg = 0.0f;                 // cell state: thread t<256 owns u=t
    __syncthreads();

    const uint32_t* ci2u = (const uint32_t*)&ci2h[0];
    const uint4* WstV = WallV + 46 * 512;    // pairs 23..39

    for (int step = 0; step < 256; ++step) {
        // ---- P1: z = ci @ [Wx;Wh] via dot2; 4-way K split, 8 cols/thread ----
        {
            float acc[8];
            #pragma unroll
            for (int m = 0; m < 8; ++m) acc[m] = 0.0f;
            uint4 ci4[10];
            const uint4* cip = (const uint4*)(ci2u + 40 * kq);
            #pragma unroll
            for (int cc = 0; cc < 10; ++cc) ci4[cc] = cip[cc];

            // registers: pairs 0..15
            #pragma unroll
            for (int p = 0; p < 16; ++p) {
                const uint32_t* cw = (const uint32_t*)&ci4[p >> 2];
                uint32_t a = cw[p & 3];
                const uint32_t* w0 = (const uint32_t*)&wr4[p * 2];
                acc[0] = dot2f(w0[0], a, acc[0]);  acc[1] = dot2f(w0[1], a, acc[1]);
                acc[2] = dot2f(w0[2], a, acc[2]);  acc[3] = dot2f(w0[3], a, acc[3]);
                acc[4] = dot2f(w0[4], a, acc[4]);  acc[5] = dot2f(w0[5], a, acc[5]);
                acc[6] = dot2f(w0[6], a, acc[6]);  acc[7] = dot2f(w0[7], a, acc[7]);
            }
            // LDS: pairs 16..22
            #pragma unroll
            for (int p = 16; p < 23; ++p) {
                const uint32_t* cw = (const uint32_t*)&ci4[p >> 2];
                uint32_t a = cw[p & 3];
                uint4 wa = Wl4[((p - 16) * 2 + 0) * 512 + t];
                uint4 wb = Wl4[((p - 16) * 2 + 1) * 512 + t];
                acc[0] = dot2f(wa.x, a, acc[0]);  acc[1] = dot2f(wa.y, a, acc[1]);
                acc[2] = dot2f(wa.z, a, acc[2]);  acc[3] = dot2f(wa.w, a, acc[3]);
                acc[4] = dot2f(wb.x, a, acc[4]);  acc[5] = dot2f(wb.y, a, acc[5]);
                acc[6] = dot2f(wb.z, a, acc[6]);  acc[7] = dot2f(wb.w, a, acc[7]);
            }
            // streamed: pairs 23..39
            #pragma unroll
            for (int p = 23; p < 40; ++p) {
                const uint32_t* cw = (const uint32_t*)&ci4[p >> 2];
                uint32_t a = cw[p & 3];
                uint4 wa = WstV[((p - 23) * 2 + 0) * 512 + t];
                uint4 wb = WstV[((p - 23) * 2 + 1) * 512 + t];
                acc[0] = dot2f(wa.x, a, acc[0]);  acc[1] = dot2f(wa.y, a, acc[1]);
                acc[2] = dot2f(wa.z, a, acc[2]);  acc[3] = dot2f(wa.w, a, acc[3]);
                acc[4] = dot2f(wb.x, a, acc[4]);  acc[5] = dot2f(wb.y, a, acc[5]);
                acc[6] = dot2f(wb.z, a, acc[6]);  acc[7] = dot2f(wb.w, a, acc[7]);
            }
            #pragma unroll
            for (int m = 0; m < 8; ++m) zpart[kq][c + 128 * m] = acc[m];
        }
        __syncthreads();   // B1

        // ---- P2: LSTM update (+ next-xt prefetch on spare threads) ----
        if (t < 256) {
            float zi = lb[t], zf = lb[256 + t], zg = lb[512 + t], zo = lb[768 + t];
            #pragma unroll
            for (int q = 0; q < 4; ++q) {
                zi += zpart[q][t];       zf += zpart[q][256 + t];
                zg += zpart[q][512 + t]; zo += zpart[q][768 + t];
            }
            float cg = sigmoidf_(zf) * c_reg + sigmoidf_(zi) * tanhf(zg);
            c_reg = cg;
            float h = sigmoidf_(zo) * tanhf(cg);
            hsh[t] = h;
            ci2h[52 + t] = (_Float16)h;
        } else if (t < 288 && step < 255) {
            int cc = t - 256;
            ci2h[cc] = (_Float16)seq[(size_t)bb * 8192 + (size_t)(step + 1) * 32 + cc];
        }
        __syncthreads();   // B2

        // ---- P3: head-param GEMM partials via dot2 (4-way u split) ----
        if (t < 368) {
            int kq2 = t / 92, col = t - kq2 * 92;
            const uint32_t* hwp = hw2G + kq2 * 32 * 92 + col;
            const uint32_t* hbp = ci2u + 26 + kq2 * 32;
            float s = 0.0f;
            #pragma unroll 8
            for (int uu = 0; uu < 32; ++uu)
                s = dot2f(hwp[uu * 92], hbp[uu], s);
            pp[kq2][col] = s;
        }
        __syncthreads();   // B3

        // ---- P4a: kv / erase / add vectors ----
        if (t < 40) {
            int hh = t / 20, wi = t % 20;
            kvs[hh][wi] = tanhf(PSCLIP1(hh * 26 + wi));
        } else if (t >= 64 && t < 104) {
            int r2 = t - 64;
            if (r2 < 20) evs[r2]      = sigmoidf_(PSCLIP1(52 + r2));
            else         avs[r2 - 20] = tanhf(PSCLIP1(72 + (r2 - 20)));
        }
        __syncthreads();   // B4

        // ---- P4b: addressing, one wave per head; lane holds n=2l,2l+1 ----
        if (t < 128) {
            const int l = t & 63, hh = t >> 6;
            const int hc = hh * 26;
            float beta  = softplusf_(PSCLIP1(hc + 20));
            float g     = sigmoidf_(PSCLIP1(hc + 21));
            float s0r = PSCLIP1(hc + 22), s1r = PSCLIP1(hc + 23), s2r = PSCLIP1(hc + 24);
            float mS = fmaxf(s0r, fmaxf(s1r, s2r));
            float q0 = expf(s0r - mS), q1 = expf(s1r - mS), q2 = expf(s2r - mS);
            float qin = 1.0f / (q0 + q1 + q2);
            float sh0 = q0 * qin, sh1 = q1 * qin, sh2 = q2 * qin;
            float gamma = softplusf_(PSCLIP1(hc + 25)) + 1.0f;

            float kvr[20]; float kn2 = 0.0f;
            #pragma unroll
            for (int wi = 0; wi < 20; ++wi) { kvr[wi] = kvs[hh][wi]; kn2 = fmaf(kvr[wi], kvr[wi], kn2); }
            float kden = sqrtf(kn2) + 1e-8f;

            float d0 = 0, d1 = 0, m20 = 0, m21 = 0;
            #pragma unroll
            for (int wi = 0; wi < 20; ++wi) {
                float2 mv = *reinterpret_cast<const float2*>(&Msh[wi][2 * l]);
                d0  = fmaf(kvr[wi], mv.x, d0);  d1  = fmaf(kvr[wi], mv.y, d1);
                m20 = fmaf(mv.x, mv.x, m20);    m21 = fmaf(mv.y, mv.y, m21);
            }
            float x0 = beta * (d0 / ((sqrtf(m20) + 1e-8f) * kden));
            float x1 = beta * (d1 / ((sqrtf(m21) + 1e-8f) * kden));
            float mx = fmaxf(x0, x1);
            #pragma unroll
            for (int o = 1; o < 64; o <<= 1) mx = fmaxf(mx, __shfl_xor(mx, o, 64));
            float e0 = expf(x0 - mx), e1 = expf(x1 - mx);
            float se = e0 + e1;
            #pragma unroll
            for (int o = 1; o < 64; o <<= 1) se += __shfl_xor(se, o, 64);
            float inv = 1.0f / se;
            float2 wpv = *reinterpret_cast<const float2*>(&wprev[hh][2 * l]);
            float wg0 = g * (e0 * inv) + (1.0f - g) * wpv.x;
            float wg1 = g * (e1 * inv) + (1.0f - g) * wpv.y;
            float wgm = __shfl(wg1, (l + 63) & 63, 64);
            float wgp = __shfl(wg0, (l + 1) & 63, 64);
            float wt0 = sh0 * wg1 + sh1 * wg0 + sh2 * wgm;
            float wt1 = sh0 * wgp + sh1 * wg1 + sh2 * wg0;
            float wpw0 = expf(gamma * logf(wt0 + 1e-8f));
            float wpw1 = expf(gamma * logf(wt1 + 1e-8f));
            float ssum = wpw0 + wpw1;
            #pragma unroll
            for (int o = 1; o < 64; o <<= 1) ssum += __shfl_xor(ssum, o, 64);
            float rin = 1.0f / ssum;
            *reinterpret_cast<float2*>(&wprev[hh][2 * l]) = make_float2(wpw0 * rin, wpw1 * rin);
        }
        __syncthreads();   // B5

        // ---- P5: reads = w_read @ M (old M), 16-lane groups ----
        if (t < 320) {
            int wi = t >> 4, l16 = t & 15;
            int n0 = l16 * 8;
            float s = 0.0f;
            #pragma unroll
            for (int n = n0; n < n0 + 8; ++n)
                s = fmaf(wprev[0][n], Msh[wi][n], s);
            #pragma unroll
            for (int o = 1; o < 16; o <<= 1) s += __shfl_xor(s, o, 64);
            if (l16 == 0) { rds[wi] = s; ci2h[32 + wi] = (_Float16)s; }
        }
        __syncthreads();   // B6

        // ---- P6: memory erase+add ----
        for (int i = t; i < MW * NLOC; i += 512) {
            int wi = i >> 7, n = i & 127;
            float wwn = wprev[1][n];
            Msh[wi][n] = Msh[wi][n] * (1.0f - wwn * evs[wi]) + wwn * avs[wi];
        }
        __syncthreads();   // B7
    }

    // ---- final NTM output head + dense + softmax ----
    if (t < 8) {
        float s = ob[t];
        for (int u = 0; u < 256; ++u) s = fmaf(hsh[u], ow[u * 8 + t], s);
        #pragma unroll
        for (int wi = 0; wi < 20; ++wi) s = fmaf(rds[wi], ow[(256 + wi) * 8 + t], s);
        o8[t] = fminf(fmaxf(s, -CLIPV), CLIPV);
    }
    __syncthreads();
    if (t == 0) {
        float l0 = db[0], l1 = db[1];
        #pragma unroll
        for (int k = 0; k < 8; ++k) {
            float v = o8[k];
            l0 = fmaf(v, dw[k * 2 + 0], l0);
            l1 = fmaf(v, dw[k * 2 + 1], l1);
        }
        float m = fmaxf(l0, l1);
        float q0 = expf(l0 - m), q1 = expf(l1 - m);
        float inv = 1.0f / (q0 + q1);
        out[bb * 2 + 0] = q0 * inv;
        out[bb * 2 + 1] = q1 * inv;
    }
}

extern "C" void kernel_launch(void* const* d_in, const int* in_sizes, int n_in,
                              void* d_out, int out_size, void* d_ws, size_t ws_size,
                              hipStream_t stream) {
    const float* inputs = (const float*)d_in[0];
    const float* c1w = (const float*)d_in[1];
    const float* c1b = (const float*)d_in[2];
    const float* c2w = (const float*)d_in[3];
    const float* c2b = (const float*)d_in[4];
    const float* lwx = (const float*)d_in[5];
    const float* lwh = (const float*)d_in[6];
    const float* lb  = (const float*)d_in[7];
    const float* hw  = (const float*)d_in[8];
    const float* hb  = (const float*)d_in[9];
    const float* ow  = (const float*)d_in[10];
    const float* ob  = (const float*)d_in[11];
    const float* dw  = (const float*)d_in[12];
    const float* db  = (const float*)d_in[13];
    float* out = (float*)d_out;

    float* ws    = (float*)d_ws;
    float* p1    = ws;                             // 4,194,304 f
    float* seq   = ws + 4194304;                   // 2,097,152 f
    uint32_t* WallG = (uint32_t*)(ws + 6291456);   // 163,840 u32
    uint32_t* hw2G  = WallG + 163840;              //  11,776 u32

    hipLaunchKernelGGL(prep_pack,  dim3(686),   dim3(256), 0, stream, lwx, lwh, hw, WallG, hw2G);
    hipLaunchKernelGGL(conv1_pool, dim3(16384), dim3(256), 0, stream, inputs, c1w, c1b, p1);
    hipLaunchKernelGGL(conv2_pool, dim3(8192),  dim3(256), 0, stream, p1, c2w, c2b, seq);
    hipLaunchKernelGGL(ntm_scan4,  dim3(256),   dim3(512), 0, stream,
                       seq, WallG, hw2G, lb, hb, ow, ob, dw, db, out);
}